// Round 6
// baseline (700.427 us; speedup 1.0000x reference)
//
#include <hip/hip_runtime.h>

#define EPS 1e-5f

static constexpr int D  = 128;
static constexpr int L  = 256;
static constexpr int C  = 256;
static constexpr int OC = 32;
static constexpr int PC = 256;

typedef __attribute__((ext_vector_type(8))) short bfrag8;   // 8 bf16 (4 VGPR)
typedef __attribute__((ext_vector_type(4))) short bhalf4;   // 4 bf16 (8B)
typedef __attribute__((ext_vector_type(4))) float f32x4;

__device__ inline unsigned short f2bf(float f) {
  union { float f; unsigned u; } v; v.f = f;
  unsigned r = v.u + 0x7FFF + ((v.u >> 16) & 1);   // RNE
  return (unsigned short)(r >> 16);
}

// ---------------- Kernel 0: prep ----------------
// Wbf3: Wout bf16, MFMA A-fragment order (M-side = p):
//   elem ((pf*32+ks)*64+lane)*8+j = Wout[p = pf*16+(lane&15)][orig(kp)],
//   kp = ks*32+(lane>>4)*8+j; kp = q*32+c -> orig = c*32+q.   (pf 0..15)
// Wlnf: [Wl|Wr] bf16, MFMA B-fragment order (N-side = out channel):
//   elem ((nf*8+ks)*64+lane)*8+j = W'[n = nf*16+(lane&15)][k = ks*32+(lane>>4)*8+j]
__global__ __launch_bounds__(256)
void prep(const float* __restrict__ Wl, const float* __restrict__ Wr,
          const float* __restrict__ Wout,
          unsigned short* __restrict__ Wbf3, unsigned short* __restrict__ Wlnf) {
  const int t = threadIdx.x, b = blockIdx.x;
  {
    const int e0 = (b * 256 + t) * 4;
    const int lane = (e0 >> 3) & 63, ks = (e0 >> 9) & 31, pf = e0 >> 14;
    const int p = pf * 16 + (lane & 15);
    unsigned short v[4];
    #pragma unroll
    for (int j = 0; j < 4; ++j) {
      const int kp = ks * 32 + ((lane >> 4) * 8) + ((e0 + j) & 7);
      const int c = kp & 31, q = kp >> 5;
      v[j] = f2bf(Wout[p * 1024 + c * 32 + q]);
    }
    *(bhalf4*)(Wbf3 + e0) = *(bhalf4*)v;
  }
  if (b < 16) {
    const int e0 = (b * 256 + t) * 4;   // < 16384
    const int lane = (e0 >> 3) & 63, ks = (e0 >> 9) & 7, nf = e0 >> 12;
    const int n = nf * 16 + (lane & 15);
    unsigned short v[4];
    #pragma unroll
    for (int j = 0; j < 4; ++j) {
      const int k = ks * 32 + ((lane >> 4) * 8) + ((e0 + j) & 7);
      v[j] = f2bf(n < 32 ? Wl[n * 256 + k] : Wr[(n - 32) * 256 + k]);
    }
    *(bhalf4*)(Wlnf + e0) = *(bhalf4*)v;
  }
}

// ---------------- Kernel 1: LayerNorm + dual projection (MFMA) ----------------
// grid (16,32): block = 8 d x 8 l = 64 rows; 256 thr = 4 waves.
__global__ __launch_bounds__(256, 4)
void ln_proj(const float* __restrict__ msa,
             const float* __restrict__ lnw, const float* __restrict__ lnb,
             const unsigned short* __restrict__ Wlnf,
             const float* __restrict__ bl, const float* __restrict__ br,
             unsigned short* __restrict__ leftT, unsigned short* __restrict__ rightT) {
  __shared__ char xb[32768];   // [64 r][256 c] bf16, swizzled ^((r&7)<<4)

  const int t = threadIdx.x, lane = t & 63, w = t >> 6;
  const int d0 = blockIdx.x * 8, l0 = blockIdx.y * 8;

  float4 xv[16];
  #pragma unroll
  for (int i = 0; i < 16; ++i) {
    const int r = i * 4 + w, dd = r & 7, ll = r >> 3;
    xv[i] = *(const float4*)(msa + ((size_t)(d0 + dd) * 256 + (l0 + ll)) * 256 + lane * 4);
  }

  float mu[16], rs[16];
  #pragma unroll
  for (int i = 0; i < 16; ++i) {
    float s  = xv[i].x + xv[i].y + xv[i].z + xv[i].w;
    float s2 = xv[i].x * xv[i].x + xv[i].y * xv[i].y + xv[i].z * xv[i].z + xv[i].w * xv[i].w;
    #pragma unroll
    for (int off = 32; off >= 1; off >>= 1) {
      s  += __shfl_xor(s, off);
      s2 += __shfl_xor(s2, off);
    }
    mu[i] = s * (1.0f / C);
    rs[i] = rsqrtf(s2 * (1.0f / C) - mu[i] * mu[i] + EPS);
  }

  {
    const float4 wv = *(const float4*)(lnw + lane * 4);
    const float4 bv = *(const float4*)(lnb + lane * 4);
    #pragma unroll
    for (int i = 0; i < 16; ++i) {
      const int r = i * 4 + w;
      float4 v = xv[i];
      unsigned short u[4];
      u[0] = f2bf((v.x - mu[i]) * rs[i] * wv.x + bv.x);
      u[1] = f2bf((v.y - mu[i]) * rs[i] * wv.y + bv.y);
      u[2] = f2bf((v.z - mu[i]) * rs[i] * wv.z + bv.z);
      u[3] = f2bf((v.w - mu[i]) * rs[i] * wv.w + bv.w);
      *(bhalf4*)&xb[r * 512 + ((lane * 8) ^ ((r & 7) << 4))] = *(bhalf4*)u;
    }
  }
  __syncthreads();

  // MFMA: M=64 rows x N=16 outs per wave, K=256
  bfrag8 wf[8];
  {
    const unsigned short* Wp = Wlnf + ((size_t)w * 8 * 64 + lane) * 8;
    #pragma unroll
    for (int ks = 0; ks < 8; ++ks) wf[ks] = *(const bfrag8*)(Wp + ks * 512);
  }
  f32x4 acc[4];
  #pragma unroll
  for (int mf = 0; mf < 4; ++mf) acc[mf] = (f32x4)0.f;
  #pragma unroll
  for (int ks = 0; ks < 8; ++ks) {
    #pragma unroll
    for (int mf = 0; mf < 4; ++mf) {
      const int row = mf * 16 + (lane & 15);
      const bfrag8 af = *(const bfrag8*)&xb[row * 512 +
                          ((ks * 64 + ((lane >> 4) << 4)) ^ ((row & 7) << 4))];
      acc[mf] = __builtin_amdgcn_mfma_f32_16x16x32_bf16(af, wf[ks], acc[mf], 0, 0, 0);
    }
  }

  // epilogue
  {
    const int n = w * 16 + (lane & 15);
    const int side = n >> 5, o = n & 31;
    const float bias = side ? br[o] : bl[o];
    const float sc = side ? (1.0f / D) : 1.0f;
    unsigned short* dst = side ? rightT : leftT;
    #pragma unroll
    for (int mf = 0; mf < 4; ++mf) {
      const int rbase = mf * 16 + ((lane >> 4) << 2);
      const int ll = rbase >> 3, ddb = rbase & 7;
      unsigned short u[4];
      #pragma unroll
      for (int r = 0; r < 4; ++r) u[r] = f2bf((acc[mf][r] + bias) * sc);
      *(bhalf4*)(dst + ((size_t)(l0 + ll) * 32 + o) * 128 + d0 + ddb) = *(bhalf4*)u;
    }
  }
}

// ---------------- Kernel 2: fused outer-product + output projection ----------------
// 1024 blocks (XCD-swizzled; tile 8l x 8m = 64 pairs), 1024 thr = 16 waves (4x4).
__global__ __launch_bounds__(1024, 8)
void fused_mfma(const unsigned short* __restrict__ leftT,
                const unsigned short* __restrict__ rightT,
                const unsigned short* __restrict__ Wbf3,
                const float* __restrict__ bout,
                float* __restrict__ out) {
  __shared__ char smem[65536];

  const int flat = blockIdx.x;
  const int wg = (flat & 7) * 128 + (flat >> 3);   // bijective (1024 % 8 == 0)
  const int mt = wg & 31, lt = wg >> 5;
  const int l0 = lt * 8, m0 = mt * 8;

  const char* Aslab = (const char*)(leftT  + (size_t)l0 * 32 * 128);  // 256 rows x 256B
  const char* Bslab = (const char*)(rightT + (size_t)m0 * 32 * 128);

  const int tid = threadIdx.x, lane = tid & 63, w = tid >> 6;
  const int wr = w >> 2, wc = w & 3;   // wave tile 64x64 of O

  f32x4 acc[4][4];
  #pragma unroll
  for (int i = 0; i < 4; ++i)
    #pragma unroll
    for (int j = 0; j < 4; ++j) acc[i][j] = (f32x4)0.f;

  // ---- Phase 1 ----
  for (int kh = 0; kh < 2; ++kh) {
    #pragma unroll
    for (int i = 0; i < 2; ++i) {
      const int lb = (i * 1024 + tid) * 16;        // 0..32KB
      const int row = lb >> 7;
      const int sb = (lb & 127) ^ ((row & 7) << 4);
      __builtin_amdgcn_global_load_lds((const void*)(Aslab + (size_t)row * 256 + kh * 128 + sb),
                                       (void*)&smem[lb], 16, 0, 0);
      __builtin_amdgcn_global_load_lds((const void*)(Bslab + (size_t)row * 256 + kh * 128 + sb),
                                       (void*)&smem[32768 + lb], 16, 0, 0);
    }
    __syncthreads();
    #pragma unroll
    for (int ks = 0; ks < 2; ++ks) {
      const int kb = ks * 64 + ((lane >> 4) << 4);
      bfrag8 a[4], b[4];
      #pragma unroll
      for (int i = 0; i < 4; ++i) {
        const int row = wr * 64 + i * 16 + (lane & 15);
        a[i] = *(const bfrag8*)&smem[(row << 7) + (kb ^ ((row & 7) << 4))];
      }
      #pragma unroll
      for (int j = 0; j < 4; ++j) {
        const int row = wc * 64 + j * 16 + (lane & 15);
        b[j] = *(const bfrag8*)&smem[32768 + (row << 7) + (kb ^ ((row & 7) << 4))];
      }
      #pragma unroll
      for (int i = 0; i < 4; ++i)
        #pragma unroll
        for (int j = 0; j < 4; ++j)
          acc[i][j] = __builtin_amdgcn_mfma_f32_16x16x32_bf16(a[i], b[j], acc[i][j], 0, 0, 0);
    }
    __syncthreads();
  }

  // pack acc -> bf16 pairs in-reg (frees 32 VGPR)
  unsigned int pk[16][2];
  #pragma unroll
  for (int i = 0; i < 4; ++i)
    #pragma unroll
    for (int j = 0; j < 4; ++j) {
      pk[i * 4 + j][0] = (unsigned)f2bf(acc[i][j][0]) | ((unsigned)f2bf(acc[i][j][1]) << 16);
      pk[i * 4 + j][1] = (unsigned)f2bf(acc[i][j][2]) | ((unsigned)f2bf(acc[i][j][3]) << 16);
    }

  // Wout fragments in registers: wave w -> p-range [w*16, w*16+16), all K
  bfrag8 wreg[32];
  {
    const unsigned short* Wp = Wbf3 + ((size_t)w * 32 * 64 + lane) * 8;
    #pragma unroll
    for (int ks = 0; ks < 32; ++ks) wreg[ks] = *(const bfrag8*)(Wp + ks * 512);
  }

  // ---- Phase 1.5 / 2: two halves of 32 pairs ----
  #pragma unroll
  for (int h = 0; h < 2; ++h) {
    if ((w >> 3) == h) {   // waves owning rows [128h,128h+128) stage this half
      #pragma unroll
      for (int i = 0; i < 4; ++i) {
        const int rowb = wr * 64 + i * 16 + ((lane >> 4) << 2);
        const int llg = rowb >> 5, cc = rowb & 31;
        #pragma unroll
        for (int j = 0; j < 4; ++j) {
          const int col = wc * 64 + j * 16 + (lane & 15);
          const int mm = col >> 5, q = col & 31;
          const int pairL = llg * 8 + mm - h * 32;          // 0..31
          const int kp = q * 32 + cc;
          const int byte = pairL * 2048 +
              ((kp * 2) ^ ((((pairL & 7) ^ ((kp >> 6) & 7)) << 4)));
          *(uint2*)&smem[byte] = make_uint2(pk[i * 4 + j][0], pk[i * 4 + j][1]);
        }
      }
    }
    __syncthreads();

    f32x4 oacc[2];
    oacc[0] = (f32x4)0.f; oacc[1] = (f32x4)0.f;
    #pragma unroll                      // FULL unroll: wreg[] indices compile-time (rule #20)
    for (int ks = 0; ks < 32; ++ks) {
      bfrag8 osf[2];
      #pragma unroll
      for (int hp = 0; hp < 2; ++hp) {
        const int pairL = hp * 16 + (lane & 15);
        const int byte = pairL * 2048 +
            ((ks * 64 + ((lane >> 4) << 4)) ^ ((((pairL & 7) ^ ((ks >> 1) & 7)) << 4)));
        osf[hp] = *(const bfrag8*)&smem[byte];
      }
      oacc[0] = __builtin_amdgcn_mfma_f32_16x16x32_bf16(wreg[ks], osf[0], oacc[0], 0, 0, 0);
      oacc[1] = __builtin_amdgcn_mfma_f32_16x16x32_bf16(wreg[ks], osf[1], oacc[1], 0, 0, 0);
    }

    // epilogue: D row = p (f32x4 over regs), col = pair
    {
      const int p0 = w * 16 + ((lane >> 4) << 2);
      const float4 bb = *(const float4*)&bout[p0];
      #pragma unroll
      for (int hp = 0; hp < 2; ++hp) {
        const int pairg = h * 32 + hp * 16 + (lane & 15);
        const int ll = pairg >> 3, mm = pairg & 7;
        float4 v;
        v.x = oacc[hp][0] + bb.x;
        v.y = oacc[hp][1] + bb.y;
        v.z = oacc[hp][2] + bb.z;
        v.w = oacc[hp][3] + bb.w;
        *(float4*)&out[((size_t)(l0 + ll) * L + (m0 + mm)) * PC + p0] = v;
      }
    }
    __syncthreads();
  }
}

extern "C" void kernel_launch(void* const* d_in, const int* in_sizes, int n_in,
                              void* d_out, int out_size, void* d_ws, size_t ws_size,
                              hipStream_t stream) {
  const float* msa  = (const float*)d_in[0];
  const float* ln_w = (const float*)d_in[1];
  const float* ln_b = (const float*)d_in[2];
  const float* Wl   = (const float*)d_in[3];
  const float* bl   = (const float*)d_in[4];
  const float* Wr   = (const float*)d_in[5];
  const float* br   = (const float*)d_in[6];
  const float* Wout = (const float*)d_in[7];
  const float* bout = (const float*)d_in[8];
  float* out = (float*)d_out;

  unsigned short* leftT  = (unsigned short*)d_ws;                 // [L*32][128] bf16 = 2 MB
  unsigned short* rightT = leftT + (size_t)L * 32 * 128;          // 2 MB
  unsigned short* Wbf3   = rightT + (size_t)L * 32 * 128;         // 512 KB (frag-packed)
  unsigned short* Wlnf   = Wbf3 + (size_t)PC * 1024;              // 32 KB (frag-packed)

  prep<<<dim3(256), 256, 0, stream>>>(Wl, Wr, Wout, Wbf3, Wlnf);
  ln_proj<<<dim3(16, 32), 256, 0, stream>>>(msa, ln_w, ln_b, Wlnf, bl, br, leftT, rightT);
  fused_mfma<<<dim3(1024), 1024, 0, stream>>>(leftT, rightT, Wbf3, bout, out);
}

// Round 7
// 96.557 us; speedup vs baseline: 7.2540x; 7.2540x over previous
//
#include <hip/hip_runtime.h>

#define EPS 1e-5f

static constexpr int D  = 128;
static constexpr int L  = 256;
static constexpr int C  = 256;
static constexpr int OC = 32;
static constexpr int PC = 256;

typedef __attribute__((ext_vector_type(8))) short bfrag8;   // 8 bf16 (4 VGPR)
typedef __attribute__((ext_vector_type(4))) short bhalf4;   // 4 bf16 (8B)
typedef __attribute__((ext_vector_type(4))) float f32x4;

__device__ inline unsigned short f2bf(float f) {
  union { float f; unsigned u; } v; v.f = f;
  unsigned r = v.u + 0x7FFF + ((v.u >> 16) & 1);   // RNE
  return (unsigned short)(r >> 16);
}

// ---------------- Kernel 0: prep ----------------
// Wbf3: Wout bf16, MFMA A-fragment order (M-side = p):
//   elem ((pf*32+ks)*64+lane)*8+j = Wout[p = pf*16+(lane&15)][orig(kp)],
//   kp = ks*32+(lane>>4)*8+j; kp = q*32+c -> orig = c*32+q.   (pf 0..15)
// Wlnf: [Wl|Wr] bf16, MFMA B-fragment order (N-side = out channel).
__global__ __launch_bounds__(256)
void prep(const float* __restrict__ Wl, const float* __restrict__ Wr,
          const float* __restrict__ Wout,
          unsigned short* __restrict__ Wbf3, unsigned short* __restrict__ Wlnf) {
  const int t = threadIdx.x, b = blockIdx.x;
  {
    const int e0 = (b * 256 + t) * 4;
    const int lane = (e0 >> 3) & 63, ks = (e0 >> 9) & 31, pf = e0 >> 14;
    const int p = pf * 16 + (lane & 15);
    unsigned short v[4];
    #pragma unroll
    for (int j = 0; j < 4; ++j) {
      const int kp = ks * 32 + ((lane >> 4) * 8) + ((e0 + j) & 7);
      const int c = kp & 31, q = kp >> 5;
      v[j] = f2bf(Wout[p * 1024 + c * 32 + q]);
    }
    *(bhalf4*)(Wbf3 + e0) = *(bhalf4*)v;
  }
  if (b < 16) {
    const int e0 = (b * 256 + t) * 4;   // < 16384
    const int lane = (e0 >> 3) & 63, ks = (e0 >> 9) & 7, nf = e0 >> 12;
    const int n = nf * 16 + (lane & 15);
    unsigned short v[4];
    #pragma unroll
    for (int j = 0; j < 4; ++j) {
      const int k = ks * 32 + ((lane >> 4) * 8) + ((e0 + j) & 7);
      v[j] = f2bf(n < 32 ? Wl[n * 256 + k] : Wr[(n - 32) * 256 + k]);
    }
    *(bhalf4*)(Wlnf + e0) = *(bhalf4*)v;
  }
}

// ---------------- Kernel 1: LayerNorm + dual projection (MFMA) ----------------
// grid (16,32): block = 8 d x 8 l = 64 rows; 256 thr = 4 waves.
__global__ __launch_bounds__(256, 4)
void ln_proj(const float* __restrict__ msa,
             const float* __restrict__ lnw, const float* __restrict__ lnb,
             const unsigned short* __restrict__ Wlnf,
             const float* __restrict__ bl, const float* __restrict__ br,
             unsigned short* __restrict__ leftT, unsigned short* __restrict__ rightT) {
  __shared__ char xb[32768];   // [64 r][256 c] bf16, swizzled ^((r&7)<<4)

  const int t = threadIdx.x, lane = t & 63, w = t >> 6;
  const int d0 = blockIdx.x * 8, l0 = blockIdx.y * 8;

  float4 xv[16];
  #pragma unroll
  for (int i = 0; i < 16; ++i) {
    const int r = i * 4 + w, dd = r & 7, ll = r >> 3;
    xv[i] = *(const float4*)(msa + ((size_t)(d0 + dd) * 256 + (l0 + ll)) * 256 + lane * 4);
  }

  float mu[16], rs[16];
  #pragma unroll
  for (int i = 0; i < 16; ++i) {
    float s  = xv[i].x + xv[i].y + xv[i].z + xv[i].w;
    float s2 = xv[i].x * xv[i].x + xv[i].y * xv[i].y + xv[i].z * xv[i].z + xv[i].w * xv[i].w;
    #pragma unroll
    for (int off = 32; off >= 1; off >>= 1) {
      s  += __shfl_xor(s, off);
      s2 += __shfl_xor(s2, off);
    }
    mu[i] = s * (1.0f / C);
    rs[i] = rsqrtf(s2 * (1.0f / C) - mu[i] * mu[i] + EPS);
  }

  {
    const float4 wv = *(const float4*)(lnw + lane * 4);
    const float4 bv = *(const float4*)(lnb + lane * 4);
    #pragma unroll
    for (int i = 0; i < 16; ++i) {
      const int r = i * 4 + w;
      float4 v = xv[i];
      unsigned short u[4];
      u[0] = f2bf((v.x - mu[i]) * rs[i] * wv.x + bv.x);
      u[1] = f2bf((v.y - mu[i]) * rs[i] * wv.y + bv.y);
      u[2] = f2bf((v.z - mu[i]) * rs[i] * wv.z + bv.z);
      u[3] = f2bf((v.w - mu[i]) * rs[i] * wv.w + bv.w);
      *(bhalf4*)&xb[r * 512 + ((lane * 8) ^ ((r & 7) << 4))] = *(bhalf4*)u;
    }
  }
  __syncthreads();

  bfrag8 wf[8];
  {
    const unsigned short* Wp = Wlnf + ((size_t)w * 8 * 64 + lane) * 8;
    #pragma unroll
    for (int ks = 0; ks < 8; ++ks) wf[ks] = *(const bfrag8*)(Wp + ks * 512);
  }
  f32x4 acc[4];
  #pragma unroll
  for (int mf = 0; mf < 4; ++mf) acc[mf] = (f32x4)0.f;
  #pragma unroll
  for (int ks = 0; ks < 8; ++ks) {
    #pragma unroll
    for (int mf = 0; mf < 4; ++mf) {
      const int row = mf * 16 + (lane & 15);
      const bfrag8 af = *(const bfrag8*)&xb[row * 512 +
                          ((ks * 64 + ((lane >> 4) << 4)) ^ ((row & 7) << 4))];
      acc[mf] = __builtin_amdgcn_mfma_f32_16x16x32_bf16(af, wf[ks], acc[mf], 0, 0, 0);
    }
  }

  {
    const int n = w * 16 + (lane & 15);
    const int side = n >> 5, o = n & 31;
    const float bias = side ? br[o] : bl[o];
    const float sc = side ? (1.0f / D) : 1.0f;
    unsigned short* dst = side ? rightT : leftT;
    #pragma unroll
    for (int mf = 0; mf < 4; ++mf) {
      const int rbase = mf * 16 + ((lane >> 4) << 2);
      const int ll = rbase >> 3, ddb = rbase & 7;
      unsigned short u[4];
      #pragma unroll
      for (int r = 0; r < 4; ++r) u[r] = f2bf((acc[mf][r] + bias) * sc);
      *(bhalf4*)(dst + ((size_t)(l0 + ll) * 32 + o) * 128 + d0 + ddb) = *(bhalf4*)u;
    }
  }
}

// ---------------- Kernel 2: fused outer-product + output projection ----------------
// 1024 blocks (XCD-swizzled; tile 8l x 8m = 64 pairs), 512 thr = 8 waves (2x4).
// Phase 1: O[256][256] = A(256xK128) B(256xK128)^T, acc 128 VGPR/thread.
// Phase 1.5: acc -> Os[64 pairs][1024 k'] bf16 in 128KB LDS (swizzle S=(pair&7)^((q>>1)&7)).
// Phase 2: single pass; Wout frags STREAMED from L2 (iteration-local, no reg residency).
__global__ __launch_bounds__(512, 2)
void fused_mfma(const unsigned short* __restrict__ leftT,
                const unsigned short* __restrict__ rightT,
                const unsigned short* __restrict__ Wbf3,
                const float* __restrict__ bout,
                float* __restrict__ out) {
  __shared__ char smem[131072];   // phase1: A@0(32K)+B@32768(32K) per k-half; then Os 128K

  const int flat = blockIdx.x;
  const int wg = (flat & 7) * 128 + (flat >> 3);   // bijective (1024 % 8 == 0)
  const int mt = wg & 31, lt = wg >> 5;
  const int l0 = lt * 8, m0 = mt * 8;

  const char* Aslab = (const char*)(leftT  + (size_t)l0 * 32 * 128);  // 256 rows x 256B
  const char* Bslab = (const char*)(rightT + (size_t)m0 * 32 * 128);

  const int tid = threadIdx.x, lane = tid & 63, w = tid >> 6;
  const int wr = w >> 2, wc = w & 3;   // wave tile 128x64 of O

  f32x4 acc[8][4];
  #pragma unroll
  for (int i = 0; i < 8; ++i)
    #pragma unroll
    for (int j = 0; j < 4; ++j) acc[i][j] = (f32x4)0.f;

  // ---- Phase 1: K=128 in two 64-halves ----
  for (int kh = 0; kh < 2; ++kh) {
    #pragma unroll
    for (int i = 0; i < 4; ++i) {
      const int lb = (i * 512 + tid) * 16;         // 0..32KB
      const int row = lb >> 7;                     // 128B rows (64 bf16 of k-half)
      const int sb = (lb & 127) ^ ((row & 7) << 4);
      __builtin_amdgcn_global_load_lds((const void*)(Aslab + (size_t)row * 256 + kh * 128 + sb),
                                       (void*)&smem[lb], 16, 0, 0);
      __builtin_amdgcn_global_load_lds((const void*)(Bslab + (size_t)row * 256 + kh * 128 + sb),
                                       (void*)&smem[32768 + lb], 16, 0, 0);
    }
    __syncthreads();
    #pragma unroll
    for (int ks = 0; ks < 2; ++ks) {
      const int kb = ks * 64 + ((lane >> 4) << 4);
      bfrag8 a[8], b[4];
      #pragma unroll
      for (int i = 0; i < 8; ++i) {
        const int row = wr * 128 + i * 16 + (lane & 15);
        a[i] = *(const bfrag8*)&smem[(row << 7) + (kb ^ ((row & 7) << 4))];
      }
      #pragma unroll
      for (int j = 0; j < 4; ++j) {
        const int row = wc * 64 + j * 16 + (lane & 15);
        b[j] = *(const bfrag8*)&smem[32768 + (row << 7) + (kb ^ ((row & 7) << 4))];
      }
      #pragma unroll
      for (int i = 0; i < 8; ++i)
        #pragma unroll
        for (int j = 0; j < 4; ++j)
          acc[i][j] = __builtin_amdgcn_mfma_f32_16x16x32_bf16(a[i], b[j], acc[i][j], 0, 0, 0);
    }
    __syncthreads();   // all phase-1 reads done before restage / Os writes
  }

  // ---- Phase 1.5: acc -> Os[pair][k'=q*32+c], swizzle S=(pair&7)^((q>>1)&7) ----
  {
    #pragma unroll
    for (int i = 0; i < 8; ++i) {
      const int rowb = wr * 128 + i * 16 + ((lane >> 4) << 2);
      const int ll = rowb >> 5, cc = rowb & 31;
      #pragma unroll
      for (int j = 0; j < 4; ++j) {
        const int col = wc * 64 + j * 16 + (lane & 15);
        const int mm = col >> 5, q = col & 31;
        const int pair = ll * 8 + mm;                       // 0..63
        const int kp = q * 32 + cc;
        const int S = (pair & 7) ^ ((q >> 1) & 7);
        const int byte = pair * 2048 + ((kp * 2) ^ (S << 4));
        uint2 u;
        u.x = (unsigned)f2bf(acc[i][j][0]) | ((unsigned)f2bf(acc[i][j][1]) << 16);
        u.y = (unsigned)f2bf(acc[i][j][2]) | ((unsigned)f2bf(acc[i][j][3]) << 16);
        *(uint2*)&smem[byte] = u;
      }
    }
  }
  __syncthreads();

  // ---- Phase 2: OUT[256 p][64 pairs] = Wbf3 x Os, K=1024; Wout streamed ----
  f32x4 oacc[2][4];
  #pragma unroll
  for (int u = 0; u < 2; ++u)
    #pragma unroll
    for (int pj = 0; pj < 4; ++pj) oacc[u][pj] = (f32x4)0.f;

  #pragma unroll 4
  for (int ks = 0; ks < 32; ++ks) {
    bfrag8 wf[2], osf[4];
    #pragma unroll
    for (int u = 0; u < 2; ++u) {
      const int pf = w * 2 + u;
      wf[u] = *(const bfrag8*)(Wbf3 + (((size_t)pf * 32 + ks) * 64 + lane) * 8);
    }
    #pragma unroll
    for (int pj = 0; pj < 4; ++pj) {
      const int pair = pj * 16 + (lane & 15);
      const int S = (pair & 7) ^ ((ks >> 1) & 7);
      const int byte = pair * 2048 + ((ks * 64 + ((lane >> 4) << 4)) ^ (S << 4));
      osf[pj] = *(const bfrag8*)&smem[byte];
    }
    #pragma unroll
    for (int u = 0; u < 2; ++u)
      #pragma unroll
      for (int pj = 0; pj < 4; ++pj)
        oacc[u][pj] = __builtin_amdgcn_mfma_f32_16x16x32_bf16(wf[u], osf[pj], oacc[u][pj], 0, 0, 0);
  }

  // ---- epilogue: row = p (regs), col = pair ----
  {
    #pragma unroll
    for (int u = 0; u < 2; ++u) {
      const int p0 = (w * 2 + u) * 16 + ((lane >> 4) << 2);
      const float4 bb = *(const float4*)&bout[p0];
      #pragma unroll
      for (int pj = 0; pj < 4; ++pj) {
        const int pair = pj * 16 + (lane & 15);
        const int ll = pair >> 3, mm = pair & 7;
        float4 v;
        v.x = oacc[u][pj][0] + bb.x;
        v.y = oacc[u][pj][1] + bb.y;
        v.z = oacc[u][pj][2] + bb.z;
        v.w = oacc[u][pj][3] + bb.w;
        *(float4*)&out[((size_t)(l0 + ll) * L + (m0 + mm)) * PC + p0] = v;
      }
    }
  }
}

extern "C" void kernel_launch(void* const* d_in, const int* in_sizes, int n_in,
                              void* d_out, int out_size, void* d_ws, size_t ws_size,
                              hipStream_t stream) {
  const float* msa  = (const float*)d_in[0];
  const float* ln_w = (const float*)d_in[1];
  const float* ln_b = (const float*)d_in[2];
  const float* Wl   = (const float*)d_in[3];
  const float* bl   = (const float*)d_in[4];
  const float* Wr   = (const float*)d_in[5];
  const float* br   = (const float*)d_in[6];
  const float* Wout = (const float*)d_in[7];
  const float* bout = (const float*)d_in[8];
  float* out = (float*)d_out;

  unsigned short* leftT  = (unsigned short*)d_ws;                 // [L*32][128] bf16 = 2 MB
  unsigned short* rightT = leftT + (size_t)L * 32 * 128;          // 2 MB
  unsigned short* Wbf3   = rightT + (size_t)L * 32 * 128;         // 512 KB (frag-packed)
  unsigned short* Wlnf   = Wbf3 + (size_t)PC * 1024;              // 32 KB (frag-packed)

  prep<<<dim3(256), 256, 0, stream>>>(Wl, Wr, Wout, Wbf3, Wlnf);
  ln_proj<<<dim3(16, 32), 256, 0, stream>>>(msa, ln_w, ln_b, Wlnf, bl, br, leftT, rightT);
  fused_mfma<<<dim3(1024), 512, 0, stream>>>(leftT, rightT, Wbf3, bout, out);
}

// Round 8
// 89.453 us; speedup vs baseline: 7.8301x; 1.0794x over previous
//
#include <hip/hip_runtime.h>

#define EPS 1e-5f

static constexpr int D  = 128;
static constexpr int L  = 256;
static constexpr int C  = 256;
static constexpr int OC = 32;
static constexpr int PC = 256;

typedef __attribute__((ext_vector_type(8))) short bfrag8;   // 8 bf16 (4 VGPR)
typedef __attribute__((ext_vector_type(4))) short bhalf4;   // 4 bf16 (8B)
typedef __attribute__((ext_vector_type(4))) float f32x4;

__device__ inline unsigned short f2bf(float f) {
  union { float f; unsigned u; } v; v.f = f;
  unsigned r = v.u + 0x7FFF + ((v.u >> 16) & 1);   // RNE
  return (unsigned short)(r >> 16);
}

// ---------------- Kernel 0: prep ----------------
// Wbf3: Wout bf16, MFMA A-fragment order (M-side = p):
//   elem ((pf*32+ks)*64+lane)*8+j = Wout[p = pf*16+(lane&15)][orig(kp)],
//   kp = ks*32+(lane>>4)*8+j; kp = q*32+c -> orig = c*32+q.   (pf 0..15)
// Wlnf: [Wl|Wr] bf16, MFMA B-fragment order (N-side = out channel).
__global__ __launch_bounds__(256)
void prep(const float* __restrict__ Wl, const float* __restrict__ Wr,
          const float* __restrict__ Wout,
          unsigned short* __restrict__ Wbf3, unsigned short* __restrict__ Wlnf) {
  const int t = threadIdx.x, b = blockIdx.x;
  {
    const int e0 = (b * 256 + t) * 4;
    const int lane = (e0 >> 3) & 63, ks = (e0 >> 9) & 31, pf = e0 >> 14;
    const int p = pf * 16 + (lane & 15);
    unsigned short v[4];
    #pragma unroll
    for (int j = 0; j < 4; ++j) {
      const int kp = ks * 32 + ((lane >> 4) * 8) + ((e0 + j) & 7);
      const int c = kp & 31, q = kp >> 5;
      v[j] = f2bf(Wout[p * 1024 + c * 32 + q]);
    }
    *(bhalf4*)(Wbf3 + e0) = *(bhalf4*)v;
  }
  if (b < 16) {
    const int e0 = (b * 256 + t) * 4;   // < 16384
    const int lane = (e0 >> 3) & 63, ks = (e0 >> 9) & 7, nf = e0 >> 12;
    const int n = nf * 16 + (lane & 15);
    unsigned short v[4];
    #pragma unroll
    for (int j = 0; j < 4; ++j) {
      const int k = ks * 32 + ((lane >> 4) * 8) + ((e0 + j) & 7);
      v[j] = f2bf(n < 32 ? Wl[n * 256 + k] : Wr[(n - 32) * 256 + k]);
    }
    *(bhalf4*)(Wlnf + e0) = *(bhalf4*)v;
  }
}

// ---------------- Kernel 1: LayerNorm + dual projection (MFMA) ----------------
// grid (16,32): block = 8 d x 8 l = 64 rows; 256 thr = 4 waves.
__global__ __launch_bounds__(256, 4)
void ln_proj(const float* __restrict__ msa,
             const float* __restrict__ lnw, const float* __restrict__ lnb,
             const unsigned short* __restrict__ Wlnf,
             const float* __restrict__ bl, const float* __restrict__ br,
             unsigned short* __restrict__ leftT, unsigned short* __restrict__ rightT) {
  __shared__ char xb[32768];   // [64 r][256 c] bf16, swizzled ^((r&7)<<4)

  const int t = threadIdx.x, lane = t & 63, w = t >> 6;
  const int d0 = blockIdx.x * 8, l0 = blockIdx.y * 8;

  float4 xv[16];
  #pragma unroll
  for (int i = 0; i < 16; ++i) {
    const int r = i * 4 + w, dd = r & 7, ll = r >> 3;
    xv[i] = *(const float4*)(msa + ((size_t)(d0 + dd) * 256 + (l0 + ll)) * 256 + lane * 4);
  }

  float mu[16], rs[16];
  #pragma unroll
  for (int i = 0; i < 16; ++i) {
    float s  = xv[i].x + xv[i].y + xv[i].z + xv[i].w;
    float s2 = xv[i].x * xv[i].x + xv[i].y * xv[i].y + xv[i].z * xv[i].z + xv[i].w * xv[i].w;
    #pragma unroll
    for (int off = 32; off >= 1; off >>= 1) {
      s  += __shfl_xor(s, off);
      s2 += __shfl_xor(s2, off);
    }
    mu[i] = s * (1.0f / C);
    rs[i] = rsqrtf(s2 * (1.0f / C) - mu[i] * mu[i] + EPS);
  }

  {
    const float4 wv = *(const float4*)(lnw + lane * 4);
    const float4 bv = *(const float4*)(lnb + lane * 4);
    #pragma unroll
    for (int i = 0; i < 16; ++i) {
      const int r = i * 4 + w;
      float4 v = xv[i];
      unsigned short u[4];
      u[0] = f2bf((v.x - mu[i]) * rs[i] * wv.x + bv.x);
      u[1] = f2bf((v.y - mu[i]) * rs[i] * wv.y + bv.y);
      u[2] = f2bf((v.z - mu[i]) * rs[i] * wv.z + bv.z);
      u[3] = f2bf((v.w - mu[i]) * rs[i] * wv.w + bv.w);
      *(bhalf4*)&xb[r * 512 + ((lane * 8) ^ ((r & 7) << 4))] = *(bhalf4*)u;
    }
  }
  __syncthreads();

  bfrag8 wf[8];
  {
    const unsigned short* Wp = Wlnf + ((size_t)w * 8 * 64 + lane) * 8;
    #pragma unroll
    for (int ks = 0; ks < 8; ++ks) wf[ks] = *(const bfrag8*)(Wp + ks * 512);
  }
  f32x4 acc[4];
  #pragma unroll
  for (int mf = 0; mf < 4; ++mf) acc[mf] = (f32x4)0.f;
  #pragma unroll
  for (int ks = 0; ks < 8; ++ks) {
    #pragma unroll
    for (int mf = 0; mf < 4; ++mf) {
      const int row = mf * 16 + (lane & 15);
      const bfrag8 af = *(const bfrag8*)&xb[row * 512 +
                          ((ks * 64 + ((lane >> 4) << 4)) ^ ((row & 7) << 4))];
      acc[mf] = __builtin_amdgcn_mfma_f32_16x16x32_bf16(af, wf[ks], acc[mf], 0, 0, 0);
    }
  }

  {
    const int n = w * 16 + (lane & 15);
    const int side = n >> 5, o = n & 31;
    const float bias = side ? br[o] : bl[o];
    const float sc = side ? (1.0f / D) : 1.0f;
    unsigned short* dst = side ? rightT : leftT;
    #pragma unroll
    for (int mf = 0; mf < 4; ++mf) {
      const int rbase = mf * 16 + ((lane >> 4) << 2);
      const int ll = rbase >> 3, ddb = rbase & 7;
      unsigned short u[4];
      #pragma unroll
      for (int r = 0; r < 4; ++r) u[r] = f2bf((acc[mf][r] + bias) * sc);
      *(bhalf4*)(dst + ((size_t)(l0 + ll) * 32 + o) * 128 + d0 + ddb) = *(bhalf4*)u;
    }
  }
}

// ---------------- Kernel 2: fused outer-product + output projection ----------------
// 2048 blocks (XCD-swizzled; tile 4l x 8m = 32 pairs), 512 thr = 8 waves (2x4).
// LDS peak 64 KB + VGPR<=128 -> 2 blocks/CU (16 waves/CU): block n's phase-2
// (L2-streamed Wout) overlaps block n+1's phase-1 (MFMA+staging).
__global__ __launch_bounds__(512, 4)
void fused_mfma(const unsigned short* __restrict__ leftT,
                const unsigned short* __restrict__ rightT,
                const unsigned short* __restrict__ Wbf3,
                const float* __restrict__ bout,
                float* __restrict__ out) {
  __shared__ char smem[65536];   // phase1: A@0(16K)+B@16384(32K) per k-half; then Os 64K

  const int flat = blockIdx.x;
  const int wg = (flat & 7) * 256 + (flat >> 3);   // bijective (2048 % 8 == 0)
  const int mt = wg & 31, lt = wg >> 5;            // 64 l-tiles x 32 m-tiles
  const int l0 = lt * 4, m0 = mt * 8;

  const char* Aslab = (const char*)(leftT  + (size_t)l0 * 32 * 128);  // 128 rows x 256B
  const char* Bslab = (const char*)(rightT + (size_t)m0 * 32 * 128);  // 256 rows x 256B

  const int tid = threadIdx.x, lane = tid & 63, w = tid >> 6;
  const int wr = w >> 2, wc = w & 3;   // wave tile 64x64 of O (128 rows x 256 cols)

  f32x4 acc[4][4];
  #pragma unroll
  for (int i = 0; i < 4; ++i)
    #pragma unroll
    for (int j = 0; j < 4; ++j) acc[i][j] = (f32x4)0.f;

  // ---- Phase 1: K=128 in two 64-halves ----
  for (int kh = 0; kh < 2; ++kh) {
    #pragma unroll
    for (int i = 0; i < 2; ++i) {     // A: 16KB
      const int lb = (i * 512 + tid) * 16;
      const int row = lb >> 7;
      const int sb = (lb & 127) ^ ((row & 7) << 4);
      __builtin_amdgcn_global_load_lds((const void*)(Aslab + (size_t)row * 256 + kh * 128 + sb),
                                       (void*)&smem[lb], 16, 0, 0);
    }
    #pragma unroll
    for (int i = 0; i < 4; ++i) {     // B: 32KB
      const int lb = (i * 512 + tid) * 16;
      const int row = lb >> 7;
      const int sb = (lb & 127) ^ ((row & 7) << 4);
      __builtin_amdgcn_global_load_lds((const void*)(Bslab + (size_t)row * 256 + kh * 128 + sb),
                                       (void*)&smem[16384 + lb], 16, 0, 0);
    }
    __syncthreads();
    #pragma unroll
    for (int ks = 0; ks < 2; ++ks) {
      const int kb = ks * 64 + ((lane >> 4) << 4);
      bfrag8 a[4], b[4];
      #pragma unroll
      for (int i = 0; i < 4; ++i) {
        const int row = wr * 64 + i * 16 + (lane & 15);
        a[i] = *(const bfrag8*)&smem[(row << 7) + (kb ^ ((row & 7) << 4))];
      }
      #pragma unroll
      for (int j = 0; j < 4; ++j) {
        const int row = wc * 64 + j * 16 + (lane & 15);
        b[j] = *(const bfrag8*)&smem[16384 + (row << 7) + (kb ^ ((row & 7) << 4))];
      }
      #pragma unroll
      for (int i = 0; i < 4; ++i)
        #pragma unroll
        for (int j = 0; j < 4; ++j)
          acc[i][j] = __builtin_amdgcn_mfma_f32_16x16x32_bf16(a[i], b[j], acc[i][j], 0, 0, 0);
    }
    __syncthreads();   // all phase-1 reads done before restage / Os writes
  }

  // ---- Phase 1.5: acc -> Os[pair 0..31][k'=q*32+c], swizzle S=(pair&7)^((q>>1)&7) ----
  {
    #pragma unroll
    for (int i = 0; i < 4; ++i) {
      const int rowb = wr * 64 + i * 16 + ((lane >> 4) << 2);
      const int ll = rowb >> 5, cc = rowb & 31;
      #pragma unroll
      for (int j = 0; j < 4; ++j) {
        const int col = wc * 64 + j * 16 + (lane & 15);
        const int mm = col >> 5, q = col & 31;
        const int pair = ll * 8 + mm;                       // 0..31
        const int kp = q * 32 + cc;
        const int S = (pair & 7) ^ ((q >> 1) & 7);
        const int byte = pair * 2048 + ((kp * 2) ^ (S << 4));
        uint2 u;
        u.x = (unsigned)f2bf(acc[i][j][0]) | ((unsigned)f2bf(acc[i][j][1]) << 16);
        u.y = (unsigned)f2bf(acc[i][j][2]) | ((unsigned)f2bf(acc[i][j][3]) << 16);
        *(uint2*)&smem[byte] = u;
      }
    }
  }
  __syncthreads();

  // ---- Phase 2: OUT[256 p][32 pairs] = Wbf3 x Os, K=1024; Wout streamed from L2 ----
  f32x4 oacc[2][2];
  #pragma unroll
  for (int u = 0; u < 2; ++u)
    #pragma unroll
    for (int pj = 0; pj < 2; ++pj) oacc[u][pj] = (f32x4)0.f;

  #pragma unroll 2
  for (int ks = 0; ks < 32; ++ks) {
    bfrag8 wf[2], osf[2];
    #pragma unroll
    for (int u = 0; u < 2; ++u) {
      const int pf = w * 2 + u;
      wf[u] = *(const bfrag8*)(Wbf3 + (((size_t)pf * 32 + ks) * 64 + lane) * 8);
    }
    #pragma unroll
    for (int pj = 0; pj < 2; ++pj) {
      const int pair = pj * 16 + (lane & 15);
      const int S = (pair & 7) ^ ((ks >> 1) & 7);
      const int byte = pair * 2048 + ((ks * 64 + ((lane >> 4) << 4)) ^ (S << 4));
      osf[pj] = *(const bfrag8*)&smem[byte];
    }
    #pragma unroll
    for (int u = 0; u < 2; ++u)
      #pragma unroll
      for (int pj = 0; pj < 2; ++pj)
        oacc[u][pj] = __builtin_amdgcn_mfma_f32_16x16x32_bf16(wf[u], osf[pj], oacc[u][pj], 0, 0, 0);
  }

  // ---- epilogue: row = p (regs), col = pair ----
  {
    #pragma unroll
    for (int u = 0; u < 2; ++u) {
      const int p0 = (w * 2 + u) * 16 + ((lane >> 4) << 2);
      const float4 bb = *(const float4*)&bout[p0];
      #pragma unroll
      for (int pj = 0; pj < 2; ++pj) {
        const int pair = pj * 16 + (lane & 15);
        const int ll = pair >> 3, mm = pair & 7;
        float4 v;
        v.x = oacc[u][pj][0] + bb.x;
        v.y = oacc[u][pj][1] + bb.y;
        v.z = oacc[u][pj][2] + bb.z;
        v.w = oacc[u][pj][3] + bb.w;
        *(float4*)&out[((size_t)(l0 + ll) * L + (m0 + mm)) * PC + p0] = v;
      }
    }
  }
}

extern "C" void kernel_launch(void* const* d_in, const int* in_sizes, int n_in,
                              void* d_out, int out_size, void* d_ws, size_t ws_size,
                              hipStream_t stream) {
  const float* msa  = (const float*)d_in[0];
  const float* ln_w = (const float*)d_in[1];
  const float* ln_b = (const float*)d_in[2];
  const float* Wl   = (const float*)d_in[3];
  const float* bl   = (const float*)d_in[4];
  const float* Wr   = (const float*)d_in[5];
  const float* br   = (const float*)d_in[6];
  const float* Wout = (const float*)d_in[7];
  const float* bout = (const float*)d_in[8];
  float* out = (float*)d_out;

  unsigned short* leftT  = (unsigned short*)d_ws;                 // [L*32][128] bf16 = 2 MB
  unsigned short* rightT = leftT + (size_t)L * 32 * 128;          // 2 MB
  unsigned short* Wbf3   = rightT + (size_t)L * 32 * 128;         // 512 KB (frag-packed)
  unsigned short* Wlnf   = Wbf3 + (size_t)PC * 1024;              // 32 KB (frag-packed)

  prep<<<dim3(256), 256, 0, stream>>>(Wl, Wr, Wout, Wbf3, Wlnf);
  ln_proj<<<dim3(16, 32), 256, 0, stream>>>(msa, ln_w, ln_b, Wlnf, bl, br, leftT, rightT);
  fused_mfma<<<dim3(2048), 512, 0, stream>>>(leftT, rightT, Wbf3, bout, out);
}

// Round 9
// 86.500 us; speedup vs baseline: 8.0975x; 1.0341x over previous
//
#include <hip/hip_runtime.h>

#define EPS 1e-5f

static constexpr int D  = 128;
static constexpr int L  = 256;
static constexpr int C  = 256;
static constexpr int OC = 32;
static constexpr int PC = 256;

typedef __attribute__((ext_vector_type(8))) short bfrag8;   // 8 bf16 (4 VGPR)
typedef __attribute__((ext_vector_type(4))) short bhalf4;   // 4 bf16 (8B)
typedef __attribute__((ext_vector_type(4))) float f32x4;

__device__ inline unsigned short f2bf(float f) {
  union { float f; unsigned u; } v; v.f = f;
  unsigned r = v.u + 0x7FFF + ((v.u >> 16) & 1);   // RNE
  return (unsigned short)(r >> 16);
}

// ---------------- Kernel 0: prep ----------------
// Wbf3: Wout bf16, MFMA A-fragment order (M-side = p):
//   elem ((pf*32+ks)*64+lane)*8+j = Wout[p = pf*16+(lane&15)][orig(kp)],
//   kp = ks*32+(lane>>4)*8+j; kp = q*32+c -> orig = c*32+q.   (pf 0..15)
// Wlnf: [Wl|Wr] bf16, MFMA B-fragment order (N-side = out channel).
__global__ __launch_bounds__(256)
void prep(const float* __restrict__ Wl, const float* __restrict__ Wr,
          const float* __restrict__ Wout,
          unsigned short* __restrict__ Wbf3, unsigned short* __restrict__ Wlnf) {
  const int t = threadIdx.x, b = blockIdx.x;
  {
    const int e0 = (b * 256 + t) * 4;
    const int lane = (e0 >> 3) & 63, ks = (e0 >> 9) & 31, pf = e0 >> 14;
    const int p = pf * 16 + (lane & 15);
    unsigned short v[4];
    #pragma unroll
    for (int j = 0; j < 4; ++j) {
      const int kp = ks * 32 + ((lane >> 4) * 8) + ((e0 + j) & 7);
      const int c = kp & 31, q = kp >> 5;
      v[j] = f2bf(Wout[p * 1024 + c * 32 + q]);
    }
    *(bhalf4*)(Wbf3 + e0) = *(bhalf4*)v;
  }
  if (b < 16) {
    const int e0 = (b * 256 + t) * 4;   // < 16384
    const int lane = (e0 >> 3) & 63, ks = (e0 >> 9) & 7, nf = e0 >> 12;
    const int n = nf * 16 + (lane & 15);
    unsigned short v[4];
    #pragma unroll
    for (int j = 0; j < 4; ++j) {
      const int k = ks * 32 + ((lane >> 4) * 8) + ((e0 + j) & 7);
      v[j] = f2bf(n < 32 ? Wl[n * 256 + k] : Wr[(n - 32) * 256 + k]);
    }
    *(bhalf4*)(Wlnf + e0) = *(bhalf4*)v;
  }
}

// ---------------- Kernel 1: LayerNorm + dual projection (MFMA) ----------------
// grid (16,32): block = 8 d x 8 l = 64 rows; 256 thr = 4 waves.
__global__ __launch_bounds__(256, 4)
void ln_proj(const float* __restrict__ msa,
             const float* __restrict__ lnw, const float* __restrict__ lnb,
             const unsigned short* __restrict__ Wlnf,
             const float* __restrict__ bl, const float* __restrict__ br,
             unsigned short* __restrict__ leftT, unsigned short* __restrict__ rightT) {
  __shared__ char xb[32768];   // [64 r][256 c] bf16, swizzled ^((r&7)<<4)

  const int t = threadIdx.x, lane = t & 63, w = t >> 6;
  const int d0 = blockIdx.x * 8, l0 = blockIdx.y * 8;

  float4 xv[16];
  #pragma unroll
  for (int i = 0; i < 16; ++i) {
    const int r = i * 4 + w, dd = r & 7, ll = r >> 3;
    xv[i] = *(const float4*)(msa + ((size_t)(d0 + dd) * 256 + (l0 + ll)) * 256 + lane * 4);
  }

  float mu[16], rs[16];
  #pragma unroll
  for (int i = 0; i < 16; ++i) {
    float s  = xv[i].x + xv[i].y + xv[i].z + xv[i].w;
    float s2 = xv[i].x * xv[i].x + xv[i].y * xv[i].y + xv[i].z * xv[i].z + xv[i].w * xv[i].w;
    #pragma unroll
    for (int off = 32; off >= 1; off >>= 1) {
      s  += __shfl_xor(s, off);
      s2 += __shfl_xor(s2, off);
    }
    mu[i] = s * (1.0f / C);
    rs[i] = rsqrtf(s2 * (1.0f / C) - mu[i] * mu[i] + EPS);
  }

  {
    const float4 wv = *(const float4*)(lnw + lane * 4);
    const float4 bv = *(const float4*)(lnb + lane * 4);
    #pragma unroll
    for (int i = 0; i < 16; ++i) {
      const int r = i * 4 + w;
      float4 v = xv[i];
      unsigned short u[4];
      u[0] = f2bf((v.x - mu[i]) * rs[i] * wv.x + bv.x);
      u[1] = f2bf((v.y - mu[i]) * rs[i] * wv.y + bv.y);
      u[2] = f2bf((v.z - mu[i]) * rs[i] * wv.z + bv.z);
      u[3] = f2bf((v.w - mu[i]) * rs[i] * wv.w + bv.w);
      *(bhalf4*)&xb[r * 512 + ((lane * 8) ^ ((r & 7) << 4))] = *(bhalf4*)u;
    }
  }
  __syncthreads();

  bfrag8 wf[8];
  {
    const unsigned short* Wp = Wlnf + ((size_t)w * 8 * 64 + lane) * 8;
    #pragma unroll
    for (int ks = 0; ks < 8; ++ks) wf[ks] = *(const bfrag8*)(Wp + ks * 512);
  }
  f32x4 acc[4];
  #pragma unroll
  for (int mf = 0; mf < 4; ++mf) acc[mf] = (f32x4)0.f;
  #pragma unroll
  for (int ks = 0; ks < 8; ++ks) {
    #pragma unroll
    for (int mf = 0; mf < 4; ++mf) {
      const int row = mf * 16 + (lane & 15);
      const bfrag8 af = *(const bfrag8*)&xb[row * 512 +
                          ((ks * 64 + ((lane >> 4) << 4)) ^ ((row & 7) << 4))];
      acc[mf] = __builtin_amdgcn_mfma_f32_16x16x32_bf16(af, wf[ks], acc[mf], 0, 0, 0);
    }
  }

  {
    const int n = w * 16 + (lane & 15);
    const int side = n >> 5, o = n & 31;
    const float bias = side ? br[o] : bl[o];
    const float sc = side ? (1.0f / D) : 1.0f;
    unsigned short* dst = side ? rightT : leftT;
    #pragma unroll
    for (int mf = 0; mf < 4; ++mf) {
      const int rbase = mf * 16 + ((lane >> 4) << 2);
      const int ll = rbase >> 3, ddb = rbase & 7;
      unsigned short u[4];
      #pragma unroll
      for (int r = 0; r < 4; ++r) u[r] = f2bf((acc[mf][r] + bias) * sc);
      *(bhalf4*)(dst + ((size_t)(l0 + ll) * 32 + o) * 128 + d0 + ddb) = *(bhalf4*)u;
    }
  }
}

// ---------------- Kernel 2: fused outer-product + output projection ----------------
// 2048 blocks (XCD-swizzled; tile 4l x 8m = 32 pairs), 512 thr = 8 waves (2x4).
// LDS 64 KB -> 2 blocks/CU. Phase-1 A(kh=1) prefetched into LDS tail; phase-2
// software-pipelined (wf+osf prefetch, setprio around MFMA clusters).
__global__ __launch_bounds__(512, 4)
void fused_mfma(const unsigned short* __restrict__ leftT,
                const unsigned short* __restrict__ rightT,
                const unsigned short* __restrict__ Wbf3,
                const float* __restrict__ bout,
                float* __restrict__ out) {
  __shared__ char smem[65536];   // ph1: A0@0(16K), B@16384(32K), A1@49152(16K); ph2: Os 64K

  const int flat = blockIdx.x;
  const int wg = (flat & 7) * 256 + (flat >> 3);   // bijective (2048 % 8 == 0)
  const int mt = wg & 31, lt = wg >> 5;            // 64 l-tiles x 32 m-tiles
  const int l0 = lt * 4, m0 = mt * 8;

  const char* Aslab = (const char*)(leftT  + (size_t)l0 * 32 * 128);  // 128 rows x 256B
  const char* Bslab = (const char*)(rightT + (size_t)m0 * 32 * 128);  // 256 rows x 256B

  const int tid = threadIdx.x, lane = tid & 63, w = tid >> 6;
  const int wr = w >> 2, wc = w & 3;   // wave tile 64x64 of O (128 rows x 256 cols)

  f32x4 acc[4][4];
  #pragma unroll
  for (int i = 0; i < 4; ++i)
    #pragma unroll
    for (int j = 0; j < 4; ++j) acc[i][j] = (f32x4)0.f;

  // ---- staging helpers (pre-swizzled source, linear LDS dest) ----
  auto stageA = [&](int kh, int dst) {
    #pragma unroll
    for (int i = 0; i < 2; ++i) {     // 16KB
      const int lb = (i * 512 + tid) * 16;
      const int row = lb >> 7;
      const int sb = (lb & 127) ^ ((row & 7) << 4);
      __builtin_amdgcn_global_load_lds((const void*)(Aslab + (size_t)row * 256 + kh * 128 + sb),
                                       (void*)&smem[dst + lb], 16, 0, 0);
    }
  };
  auto stageB = [&](int kh) {
    #pragma unroll
    for (int i = 0; i < 4; ++i) {     // 32KB @16384
      const int lb = (i * 512 + tid) * 16;
      const int row = lb >> 7;
      const int sb = (lb & 127) ^ ((row & 7) << 4);
      __builtin_amdgcn_global_load_lds((const void*)(Bslab + (size_t)row * 256 + kh * 128 + sb),
                                       (void*)&smem[16384 + lb], 16, 0, 0);
    }
  };
  auto computeKh = [&](int abase) {
    #pragma unroll
    for (int ks = 0; ks < 2; ++ks) {
      const int kb = ks * 64 + ((lane >> 4) << 4);
      bfrag8 a[4], b[4];
      #pragma unroll
      for (int i = 0; i < 4; ++i) {
        const int row = wr * 64 + i * 16 + (lane & 15);
        a[i] = *(const bfrag8*)&smem[abase + (row << 7) + (kb ^ ((row & 7) << 4))];
      }
      #pragma unroll
      for (int j = 0; j < 4; ++j) {
        const int row = wc * 64 + j * 16 + (lane & 15);
        b[j] = *(const bfrag8*)&smem[16384 + (row << 7) + (kb ^ ((row & 7) << 4))];
      }
      __builtin_amdgcn_s_setprio(1);
      #pragma unroll
      for (int i = 0; i < 4; ++i)
        #pragma unroll
        for (int j = 0; j < 4; ++j)
          acc[i][j] = __builtin_amdgcn_mfma_f32_16x16x32_bf16(a[i], b[j], acc[i][j], 0, 0, 0);
      __builtin_amdgcn_s_setprio(0);
    }
  };

  // ---- Phase 1 ----
  stageA(0, 0);
  stageB(0);
  __syncthreads();
  stageA(1, 49152);        // issued AFTER barrier -> overlaps kh0 compute
  computeKh(0);
  __syncthreads();         // drains A1; B0 reads done
  stageB(1);
  __syncthreads();         // B1 ready
  computeKh(49152);
  __syncthreads();         // all phase-1 reads done before Os writes

  // ---- Phase 1.5: acc -> Os[pair 0..31][k'=q*32+c], swizzle S=(pair&7)^((q>>1)&7) ----
  {
    #pragma unroll
    for (int i = 0; i < 4; ++i) {
      const int rowb = wr * 64 + i * 16 + ((lane >> 4) << 2);
      const int ll = rowb >> 5, cc = rowb & 31;
      #pragma unroll
      for (int j = 0; j < 4; ++j) {
        const int col = wc * 64 + j * 16 + (lane & 15);
        const int mm = col >> 5, q = col & 31;
        const int pair = ll * 8 + mm;                       // 0..31
        const int kp = q * 32 + cc;
        const int S = (pair & 7) ^ ((q >> 1) & 7);
        const int byte = pair * 2048 + ((kp * 2) ^ (S << 4));
        uint2 u;
        u.x = (unsigned)f2bf(acc[i][j][0]) | ((unsigned)f2bf(acc[i][j][1]) << 16);
        u.y = (unsigned)f2bf(acc[i][j][2]) | ((unsigned)f2bf(acc[i][j][3]) << 16);
        *(uint2*)&smem[byte] = u;
      }
    }
  }
  __syncthreads();

  // ---- Phase 2: OUT[256 p][32 pairs], K=1024; pipelined wf (global) + osf (LDS) ----
  f32x4 oacc[2][2];
  #pragma unroll
  for (int u = 0; u < 2; ++u)
    #pragma unroll
    for (int pj = 0; pj < 2; ++pj) oacc[u][pj] = (f32x4)0.f;

  const unsigned short* wp0 = Wbf3 + (((size_t)(w * 2)     * 32) * 64 + lane) * 8;
  const unsigned short* wp1 = Wbf3 + (((size_t)(w * 2 + 1) * 32) * 64 + lane) * 8;

  auto ldos = [&](int ks, bfrag8* o) {
    #pragma unroll
    for (int pj = 0; pj < 2; ++pj) {
      const int pair = pj * 16 + (lane & 15);
      const int S = (pair & 7) ^ ((ks >> 1) & 7);
      o[pj] = *(const bfrag8*)&smem[pair * 2048 + ((ks * 64 + ((lane >> 4) << 4)) ^ (S << 4))];
    }
  };

  bfrag8 wfA0 = *(const bfrag8*)(wp0);
  bfrag8 wfA1 = *(const bfrag8*)(wp1);
  bfrag8 osA[2]; ldos(0, osA);
  bfrag8 wfB0, wfB1, osB[2];

  for (int ks = 0; ks < 32; ks += 2) {
    // prefetch odd slot
    wfB0 = *(const bfrag8*)(wp0 + (ks + 1) * 512);
    wfB1 = *(const bfrag8*)(wp1 + (ks + 1) * 512);
    ldos(ks + 1, osB);
    __builtin_amdgcn_s_setprio(1);
    oacc[0][0] = __builtin_amdgcn_mfma_f32_16x16x32_bf16(wfA0, osA[0], oacc[0][0], 0, 0, 0);
    oacc[0][1] = __builtin_amdgcn_mfma_f32_16x16x32_bf16(wfA0, osA[1], oacc[0][1], 0, 0, 0);
    oacc[1][0] = __builtin_amdgcn_mfma_f32_16x16x32_bf16(wfA1, osA[0], oacc[1][0], 0, 0, 0);
    oacc[1][1] = __builtin_amdgcn_mfma_f32_16x16x32_bf16(wfA1, osA[1], oacc[1][1], 0, 0, 0);
    __builtin_amdgcn_s_setprio(0);
    if (ks + 2 < 32) {   // prefetch next even slot
      wfA0 = *(const bfrag8*)(wp0 + (ks + 2) * 512);
      wfA1 = *(const bfrag8*)(wp1 + (ks + 2) * 512);
      ldos(ks + 2, osA);
    }
    __builtin_amdgcn_s_setprio(1);
    oacc[0][0] = __builtin_amdgcn_mfma_f32_16x16x32_bf16(wfB0, osB[0], oacc[0][0], 0, 0, 0);
    oacc[0][1] = __builtin_amdgcn_mfma_f32_16x16x32_bf16(wfB0, osB[1], oacc[0][1], 0, 0, 0);
    oacc[1][0] = __builtin_amdgcn_mfma_f32_16x16x32_bf16(wfB1, osB[0], oacc[1][0], 0, 0, 0);
    oacc[1][1] = __builtin_amdgcn_mfma_f32_16x16x32_bf16(wfB1, osB[1], oacc[1][1], 0, 0, 0);
    __builtin_amdgcn_s_setprio(0);
  }

  // ---- epilogue: row = p (regs), col = pair ----
  {
    #pragma unroll
    for (int u = 0; u < 2; ++u) {
      const int p0 = (w * 2 + u) * 16 + ((lane >> 4) << 2);
      const float4 bb = *(const float4*)&bout[p0];
      #pragma unroll
      for (int pj = 0; pj < 2; ++pj) {
        const int pair = pj * 16 + (lane & 15);
        const int ll = pair >> 3, mm = pair & 7;
        float4 v;
        v.x = oacc[u][pj][0] + bb.x;
        v.y = oacc[u][pj][1] + bb.y;
        v.z = oacc[u][pj][2] + bb.z;
        v.w = oacc[u][pj][3] + bb.w;
        *(float4*)&out[((size_t)(l0 + ll) * L + (m0 + mm)) * PC + p0] = v;
      }
    }
  }
}

extern "C" void kernel_launch(void* const* d_in, const int* in_sizes, int n_in,
                              void* d_out, int out_size, void* d_ws, size_t ws_size,
                              hipStream_t stream) {
  const float* msa  = (const float*)d_in[0];
  const float* ln_w = (const float*)d_in[1];
  const float* ln_b = (const float*)d_in[2];
  const float* Wl   = (const float*)d_in[3];
  const float* bl   = (const float*)d_in[4];
  const float* Wr   = (const float*)d_in[5];
  const float* br   = (const float*)d_in[6];
  const float* Wout = (const float*)d_in[7];
  const float* bout = (const float*)d_in[8];
  float* out = (float*)d_out;

  unsigned short* leftT  = (unsigned short*)d_ws;                 // [L*32][128] bf16 = 2 MB
  unsigned short* rightT = leftT + (size_t)L * 32 * 128;          // 2 MB
  unsigned short* Wbf3   = rightT + (size_t)L * 32 * 128;         // 512 KB (frag-packed)
  unsigned short* Wlnf   = Wbf3 + (size_t)PC * 1024;              // 32 KB (frag-packed)

  prep<<<dim3(256), 256, 0, stream>>>(Wl, Wr, Wout, Wbf3, Wlnf);
  ln_proj<<<dim3(16, 32), 256, 0, stream>>>(msa, ln_w, ln_b, Wlnf, bl, br, leftT, rightT);
  fused_mfma<<<dim3(2048), 512, 0, stream>>>(leftT, rightT, Wbf3, bout, out);
}